// Round 6
// baseline (265.718 us; speedup 1.0000x reference)
//
#include <hip/hip_runtime.h>
#include <math.h>

#define N_NODES 50000
#define N_EDGES 400000
#define N_TOT   450000   /* edges + self-loops */
#define NEG 0.2f
#define CAP 64           /* edge bucket capacity; deg = Poisson(8)+1, max over dataset ~27 */

typedef __attribute__((ext_vector_type(8))) short bf16x8;
typedef __attribute__((ext_vector_type(8))) unsigned short u16x8;
typedef __attribute__((ext_vector_type(4))) float f32x4;

__device__ __forceinline__ float lrelu(float x) { return x > 0.f ? x : NEG * x; }

__device__ __forceinline__ unsigned short f2bf(float f) {
    unsigned u = __float_as_uint(f);
    unsigned r = u + 0x7FFFu + ((u >> 16) & 1u);   /* RNE */
    return (unsigned short)(r >> 16);
}
__device__ __forceinline__ float bf2f(unsigned short h) {
    return __uint_as_float(((unsigned)h) << 16);
}

/* ---------------- init: weight prep (W1/W2 hi, W1a hi+lo) + cursor zero ---------------- */
__global__ void k_init(const float* __restrict__ W1, unsigned short* W1hiT,
                       const float* __restrict__ W2, unsigned short* W2hiT,
                       const float* __restrict__ a1s, const float* __restrict__ a1d,
                       unsigned short* W1aThi, unsigned short* W1aTlo,
                       int* cursor) {
    int i = blockIdx.x * 256 + threadIdx.x;
    if (i < 128 * 512) {
        int col = i & 511, k = i >> 9;
        W1hiT[col * 128 + k] = f2bf(W1[k * 512 + col]);
    } else if (i < 128 * 512 + 512 * 16) {
        int j = i - 128 * 512;
        int col = j & 15, k = j >> 4;
        W2hiT[col * 512 + k] = f2bf(W2[k * 16 + col]);
    } else if (i < 128 * 512 + 512 * 16 + 128 * 16) {
        int j = i - (128 * 512 + 512 * 16);
        int c16 = j & 15, k = j >> 4;
        int hd = c16 & 7;
        const float* av = (c16 < 8) ? a1s : a1d;
        float acc = 0.f;
#pragma unroll 8
        for (int c = 0; c < 64; c++)
            acc = fmaf(W1[k * 512 + hd * 64 + c], av[hd * 64 + c], acc);
        unsigned short h = f2bf(acc);
        W1aThi[c16 * 128 + k] = h;
        W1aTlo[c16 * 128 + k] = f2bf(acc - bf2f(h));
    } else {
        int j = i - (128 * 512 + 512 * 16 + 128 * 16);
        if (j < N_NODES) cursor[j] = 0;
    }
}

/* ---------------- merged: edge scatter-append (blocks < SCAT) + layer-1 GEMM ---------------- */
#define SCAT 256
__global__ __launch_bounds__(256) void k_sg1(const int* __restrict__ ei,
                                             int* __restrict__ cursor,
                                             int* __restrict__ colsrc,
                                             const float* __restrict__ x,
                                             const unsigned short* __restrict__ W1hiT,
                                             const unsigned short* __restrict__ W1aThi,
                                             const unsigned short* __restrict__ W1aTlo,
                                             unsigned short* __restrict__ h1b,
                                             float* __restrict__ al1s,
                                             float* __restrict__ al1d) {
    __shared__ unsigned short xs_hi[64 * 136];
    if (blockIdx.x < SCAT) {
        int gtid = blockIdx.x * 256 + threadIdx.x;
        for (int i = gtid; i < N_TOT; i += SCAT * 256) {
            int src, dst;
            if (i < N_EDGES) { src = ei[i]; dst = ei[N_EDGES + i]; }
            else             { src = dst = i - N_EDGES; }
            int pos = atomicAdd(&cursor[dst], 1);
            if (pos < CAP) colsrc[dst * CAP + pos] = src;
        }
        return;
    }
    const int t = threadIdx.x;
    const int rb = (blockIdx.x - SCAT) * 64;

#pragma unroll
    for (int i = 0; i < 8; i++) {
        int idx = t + 256 * i;           /* 2048 float4 total */
        int r = idx >> 5;                /* 32 float4 per row */
        int k = (idx & 31) * 4;
        int gr = rb + r;
        float4 v = make_float4(0.f, 0.f, 0.f, 0.f);
        if (gr < N_NODES) v = *reinterpret_cast<const float4*>(&x[gr * 128 + k]);
        ushort4 hi;
        hi.x = f2bf(v.x); hi.y = f2bf(v.y); hi.z = f2bf(v.z); hi.w = f2bf(v.w);
        *reinterpret_cast<ushort4*>(&xs_hi[r * 136 + k]) = hi;
    }
    __syncthreads();

    const int lane = t & 63;
    const int w = t >> 6;
    const int kbase = (lane >> 4) * 8;
    const int colloc = (w << 4) + (lane & 15);

#pragma unroll
    for (int pr = 0; pr < 4; pr++) {
        bf16x8 bhi[2][4];
#pragma unroll
        for (int si = 0; si < 2; si++) {
            int col = (pr * 2 + si) * 64 + colloc;
#pragma unroll
            for (int kc = 0; kc < 4; kc++)
                bhi[si][kc] = *reinterpret_cast<const bf16x8*>(&W1hiT[col * 128 + kc * 32 + kbase]);
        }
#pragma unroll
        for (int mt = 0; mt < 4; mt++) {
            const int arow = mt * 16 + (lane & 15);
            bf16x8 ah[4];
#pragma unroll
            for (int kc = 0; kc < 4; kc++)
                ah[kc] = *reinterpret_cast<const bf16x8*>(&xs_hi[arow * 136 + kc * 32 + kbase]);
#pragma unroll
            for (int si = 0; si < 2; si++) {
                f32x4 acc = {0.f, 0.f, 0.f, 0.f};
#pragma unroll
                for (int kc = 0; kc < 4; kc++)
                    acc = __builtin_amdgcn_mfma_f32_16x16x32_bf16(ah[kc], bhi[si][kc], acc, 0, 0, 0);
                const int col = (pr * 2 + si) * 64 + colloc;
                const int r0 = rb + mt * 16 + (lane >> 4) * 4;
#pragma unroll
                for (int r = 0; r < 4; r++) {
                    int row = r0 + r;
                    if (row < N_NODES) h1b[row * 512 + col] = f2bf(acc[r]);
                }
            }
        }
    }

    /* fused attention-half tile: wave w handles m-tile w, cols 0..15 of W1a (hi+lo) */
    {
        const int c16 = lane & 15;
        bf16x8 bh[4], bl[4];
#pragma unroll
        for (int kc = 0; kc < 4; kc++) {
            bh[kc] = *reinterpret_cast<const bf16x8*>(&W1aThi[c16 * 128 + kc * 32 + kbase]);
            bl[kc] = *reinterpret_cast<const bf16x8*>(&W1aTlo[c16 * 128 + kc * 32 + kbase]);
        }
        const int arow = (w << 4) + (lane & 15);
        f32x4 acc = {0.f, 0.f, 0.f, 0.f};
#pragma unroll
        for (int kc = 0; kc < 4; kc++) {
            bf16x8 ah = *reinterpret_cast<const bf16x8*>(&xs_hi[arow * 136 + kc * 32 + kbase]);
            acc = __builtin_amdgcn_mfma_f32_16x16x32_bf16(ah, bh[kc], acc, 0, 0, 0);
            acc = __builtin_amdgcn_mfma_f32_16x16x32_bf16(ah, bl[kc], acc, 0, 0, 0);
        }
        const int r0 = rb + (w << 4) + (lane >> 4) * 4;
#pragma unroll
        for (int r = 0; r < 4; r++) {
            int row = r0 + r;
            if (row < N_NODES) {
                if (c16 < 8) al1s[row * 8 + c16] = acc[r];
                else         al1d[row * 8 + (c16 - 8)] = acc[r];
            }
        }
    }
}

/* ---------------- Layer 1 softmax+agg FUSED with layer-2 GEMM ----------------
   One wave per dst node (4/block, 256 thr) — r1-exact gather (proven 70.6 us).
   BARRIER-FREE: no __syncthreads anywhere. Each wave writes its finished row to
   a PRIVATE LDS slot (wave-coherent), then runs its OWN 16x512 @ 512x16 MFMA
   with all 16 A rows = its node's row (every C row equals the output vector;
   take a2[0]). W2 fragments come from global (16 KB, L1-resident after first
   wave). Waves retire independently -> memory pipe never idles on a barrier. */
__global__ __launch_bounds__(256) void k_agg1(const int* __restrict__ cursor,
                                              const int* __restrict__ colsrc,
                                              const float* __restrict__ al1s,
                                              const float* __restrict__ al1d,
                                              const unsigned short* __restrict__ h1b,
                                              const float* __restrict__ b1,
                                              const unsigned short* __restrict__ W2hiT,
                                              const float* __restrict__ a2s,
                                              const float* __restrict__ a2d,
                                              unsigned short* __restrict__ h2b,
                                              float* __restrict__ al2s,
                                              float* __restrict__ al2d) {
    __shared__ float pw[4][8 * 66];                       /* per-wave edge weights, head-major */
    __shared__ __align__(16) unsigned short vsw[4][528];  /* per-wave finished row, bf16 */
    const int wid  = threadIdx.x >> 6;
    const int lane = threadIdx.x & 63;
    const int n = blockIdx.x * 4 + wid;                   /* grid exact: n < N_NODES always */
    const int cnt = min(cursor[n], CAP);
    const int eb = n * CAP;
    const int h  = lane >> 3;                             /* head owned by this lane */
    const int c8 = lane << 3;                             /* first of 8 owned channels */
    float* mypw = pw[wid];

    const float4 d0 = *reinterpret_cast<const float4*>(&al1d[n * 8]);
    const float4 d1 = *reinterpret_cast<const float4*>(&al1d[n * 8 + 4]);

    int s0 = 0;
    float p[8];
    if (lane < cnt) {
        s0 = colsrc[eb + lane];
        const float4 u0 = *reinterpret_cast<const float4*>(&al1s[s0 * 8]);
        const float4 u1 = *reinterpret_cast<const float4*>(&al1s[s0 * 8 + 4]);
        p[0] = __expf(fminf(lrelu(u0.x + d0.x), 60.f));
        p[1] = __expf(fminf(lrelu(u0.y + d0.y), 60.f));
        p[2] = __expf(fminf(lrelu(u0.z + d0.z), 60.f));
        p[3] = __expf(fminf(lrelu(u0.w + d0.w), 60.f));
        p[4] = __expf(fminf(lrelu(u1.x + d1.x), 60.f));
        p[5] = __expf(fminf(lrelu(u1.y + d1.y), 60.f));
        p[6] = __expf(fminf(lrelu(u1.z + d1.z), 60.f));
        p[7] = __expf(fminf(lrelu(u1.w + d1.w), 60.f));
    } else {
#pragma unroll
        for (int hh = 0; hh < 8; hh++) p[hh] = 0.f;
    }
#pragma unroll
    for (int hh = 0; hh < 8; hh++) mypw[hh * 66 + lane] = p[hh];

    float acc[8] = {0.f, 0.f, 0.f, 0.f, 0.f, 0.f, 0.f, 0.f};
    float sm = 0.f;
    const int pwh = h * 66;

    int j = 0;
    for (; j + 3 < cnt; j += 4) {
        int s[4]; float w[4]; u16x8 vv[4];
#pragma unroll
        for (int k = 0; k < 4; k++) {
            s[k] = __shfl(s0, j + k, 64);
            w[k] = mypw[pwh + j + k];
        }
#pragma unroll
        for (int k = 0; k < 4; k++)
            vv[k] = *reinterpret_cast<const u16x8*>(&h1b[s[k] * 512 + c8]);
#pragma unroll
        for (int k = 0; k < 4; k++) {
            sm += w[k];
#pragma unroll
            for (int c = 0; c < 8; c++)
                acc[c] = fmaf(w[k], bf2f(vv[k][c]), acc[c]);
        }
    }
    for (; j < cnt; ++j) {
        int s = __shfl(s0, j, 64);
        u16x8 v = *reinterpret_cast<const u16x8*>(&h1b[s * 512 + c8]);
        float w = mypw[pwh + j];
        sm += w;
#pragma unroll
        for (int c = 0; c < 8; c++) acc[c] = fmaf(w, bf2f(v[c]), acc[c]);
    }

    const float inv = 1.f / sm;
    const float4 ba = *reinterpret_cast<const float4*>(&b1[c8]);
    const float4 bb = *reinterpret_cast<const float4*>(&b1[c8 + 4]);
    float v[8];
    v[0] = acc[0] * inv + ba.x; v[1] = acc[1] * inv + ba.y;
    v[2] = acc[2] * inv + ba.z; v[3] = acc[3] * inv + ba.w;
    v[4] = acc[4] * inv + bb.x; v[5] = acc[5] * inv + bb.y;
    v[6] = acc[6] * inv + bb.z; v[7] = acc[7] * inv + bb.w;
#pragma unroll
    for (int k = 0; k < 8; k++)
        v[k] = v[k] > 0.f ? v[k] : __expf(v[k]) - 1.f;
    u16x8 o;
#pragma unroll
    for (int k = 0; k < 8; k++) o[k] = f2bf(v[k]);
    *reinterpret_cast<u16x8*>(&vsw[wid][c8]) = o;
    /* no barrier: vsw[wid] is written and read by this wave only; the compiler's
       lgkmcnt tracking orders the ds_write before the dependent ds_reads. */

    /* per-wave 16x512 @ 512x16 matvec: all 16 A rows = this node's row, so every
       C row holds the same 16-channel output; use a2[0]. */
    {
        const int col   = lane & 15;
        const int kbase = (lane >> 4) << 3;
        f32x4 a2 = {0.f, 0.f, 0.f, 0.f};
#pragma unroll 4
        for (int kc = 0; kc < 16; kc++) {
            bf16x8 bh = *reinterpret_cast<const bf16x8*>(&W2hiT[col * 512 + kc * 32 + kbase]);
            bf16x8 ah = *reinterpret_cast<const bf16x8*>(&vsw[wid][kc * 32 + kbase]);
            a2 = __builtin_amdgcn_mfma_f32_16x16x32_bf16(ah, bh, a2, 0, 0, 0);
        }
        const float ov = a2[0];
        float ps = ov * a2s[col];
        float pd = ov * a2d[col];
        ps += __shfl_xor(ps, 1, 64); pd += __shfl_xor(pd, 1, 64);
        ps += __shfl_xor(ps, 2, 64); pd += __shfl_xor(pd, 2, 64);
        ps += __shfl_xor(ps, 4, 64); pd += __shfl_xor(pd, 4, 64);
        ps += __shfl_xor(ps, 8, 64); pd += __shfl_xor(pd, 8, 64);
        if (lane < 16) h2b[n * 16 + col] = f2bf(ov);
        if (lane == 0) { al2s[n] = ps; al2d[n] = pd; }
    }
}

/* ---------------- Layer 2 aggregation -> out (8-edge-parallel, 4B h2b loads) ---------------- */
__global__ __launch_bounds__(256) void k_agg2(const int* __restrict__ cursor,
                                              const int* __restrict__ colsrc,
                                              const float* __restrict__ al2s,
                                              const float* __restrict__ al2d,
                                              const unsigned short* __restrict__ h2b,
                                              const float* __restrict__ b2,
                                              float* __restrict__ out) {
    int wv = threadIdx.x >> 6, lane = threadIdx.x & 63;
    int n = blockIdx.x * 4 + wv;
    if (n >= N_NODES) return;
    int cnt = min(cursor[n], CAP);
    const int eb = n * CAP;
    float ald = al2d[n];
    int q = lane >> 3;            /* edge slot 0..7 */
    int c2 = (lane & 7) << 1;     /* channel pair base */
    float acc0 = 0.f, acc1 = 0.f, smL = 0.f;
    for (int e = q; e < cnt; e += 8) {
        int s = colsrc[eb + e];
        float w = __expf(fminf(lrelu(al2s[s] + ald), 60.f));
        unsigned v = *reinterpret_cast<const unsigned*>(&h2b[s * 16 + c2]);
        smL += w;
        acc0 = fmaf(w, bf2f((unsigned short)(v & 0xFFFFu)), acc0);
        acc1 = fmaf(w, __uint_as_float(v & 0xFFFF0000u), acc1);
    }
    acc0 += __shfl_xor(acc0, 8, 64);  acc1 += __shfl_xor(acc1, 8, 64);  smL += __shfl_xor(smL, 8, 64);
    acc0 += __shfl_xor(acc0, 16, 64); acc1 += __shfl_xor(acc1, 16, 64); smL += __shfl_xor(smL, 16, 64);
    acc0 += __shfl_xor(acc0, 32, 64); acc1 += __shfl_xor(acc1, 32, 64); smL += __shfl_xor(smL, 32, 64);
    if (q == 0) {
        float inv = 1.f / smL;
        float2 r;
        r.x = acc0 * inv + b2[c2];
        r.y = acc1 * inv + b2[c2 + 1];
        *reinterpret_cast<float2*>(&out[n * 16 + c2]) = r;
    }
}

/* ---------------- launch ---------------- */
extern "C" void kernel_launch(void* const* d_in, const int* in_sizes, int n_in,
                              void* d_out, int out_size, void* d_ws, size_t ws_size,
                              hipStream_t stream) {
    const float* x   = (const float*)d_in[0];
    const int*   ei  = (const int*)d_in[1];
    const float* W1  = (const float*)d_in[2];
    const float* a1s = (const float*)d_in[3];
    const float* a1d = (const float*)d_in[4];
    const float* b1  = (const float*)d_in[5];
    const float* W2  = (const float*)d_in[6];
    const float* a2s = (const float*)d_in[7];
    const float* a2d = (const float*)d_in[8];
    const float* b2  = (const float*)d_in[9];
    float* out = (float*)d_out;

    char* ws = (char*)d_ws;
    unsigned short* h1b = (unsigned short*)(ws + 0);            /* N*512 bf16 = 51.2 MB */
    unsigned short* h2b = (unsigned short*)(ws + 102400000);    /* N*16 bf16 = 1.6 MB */
    float* al1s = (float*)(ws + 105600000);    /* N*8 */
    float* al1d = (float*)(ws + 107200000);    /* N*8 */
    float* al2s = (float*)(ws + 108800000);    /* N */
    float* al2d = (float*)(ws + 109000000);    /* N */
    int* cursor = (int*)(ws + 109200000);      /* N ints */
    int* colsrc = (int*)(ws + 109400000);      /* N*CAP ints = 12.8 MB */
    unsigned short* W1hiT  = (unsigned short*)(ws + 122200000); /* 512x128 bf16 */
    unsigned short* W2hiT  = (unsigned short*)(ws + 122336000); /* 16x512 bf16 */
    unsigned short* W1aThi = (unsigned short*)(ws + 122352384); /* 16x128 bf16 */
    unsigned short* W1aTlo = (unsigned short*)(ws + 122356480);

    /* init: weight prep + cursor zero (one launch) */
    k_init<<<492, 256, 0, stream>>>(W1, W1hiT, W2, W2hiT, a1s, a1d, W1aThi, W1aTlo, cursor);

    /* scatter-append + layer-1 GEMM (merged) */
    k_sg1<<<SCAT + (N_NODES + 63) / 64, 256, 0, stream>>>(ei, cursor, colsrc, x,
                                                          W1hiT, W1aThi, W1aTlo,
                                                          h1b, al1s, al1d);

    /* layer 1 aggregation fused with layer-2 GEMM (barrier-free, per-wave epilogue) */
    k_agg1<<<(N_NODES + 3) / 4, 256, 0, stream>>>(cursor, colsrc, al1s, al1d, h1b, b1,
                                                  W2hiT, a2s, a2d, h2b, al2s, al2d);

    /* layer 2 aggregation */
    k_agg2<<<(N_NODES + 3) / 4, 256, 0, stream>>>(cursor, colsrc, al2s, al2d, h2b, b2, out);
}

// Round 7
// 223.923 us; speedup vs baseline: 1.1866x; 1.1866x over previous
//
#include <hip/hip_runtime.h>
#include <math.h>

#define N_NODES 50000
#define N_EDGES 400000
#define N_TOT   450000   /* edges + self-loops */
#define NEG 0.2f
#define CAP 64           /* edge bucket capacity; deg = Poisson(8)+1, max over dataset ~27 */

typedef __attribute__((ext_vector_type(8))) short bf16x8;
typedef __attribute__((ext_vector_type(8))) unsigned short u16x8;
typedef __attribute__((ext_vector_type(4))) float f32x4;

__device__ __forceinline__ float lrelu(float x) { return x > 0.f ? x : NEG * x; }

__device__ __forceinline__ unsigned short f2bf(float f) {
    unsigned u = __float_as_uint(f);
    unsigned r = u + 0x7FFFu + ((u >> 16) & 1u);   /* RNE */
    return (unsigned short)(r >> 16);
}
__device__ __forceinline__ float bf2f(unsigned short h) {
    return __uint_as_float(((unsigned)h) << 16);
}

/* ---------------- init: weight prep (W1/W2 hi, W1a hi+lo) + cursor zero ---------------- */
__global__ void k_init(const float* __restrict__ W1, unsigned short* W1hiT,
                       const float* __restrict__ W2, unsigned short* W2hiT,
                       const float* __restrict__ a1s, const float* __restrict__ a1d,
                       unsigned short* W1aThi, unsigned short* W1aTlo,
                       int* cursor) {
    int i = blockIdx.x * 256 + threadIdx.x;
    if (i < 128 * 512) {
        int col = i & 511, k = i >> 9;
        W1hiT[col * 128 + k] = f2bf(W1[k * 512 + col]);
    } else if (i < 128 * 512 + 512 * 16) {
        int j = i - 128 * 512;
        int col = j & 15, k = j >> 4;
        W2hiT[col * 512 + k] = f2bf(W2[k * 16 + col]);
    } else if (i < 128 * 512 + 512 * 16 + 128 * 16) {
        int j = i - (128 * 512 + 512 * 16);
        int c16 = j & 15, k = j >> 4;
        int hd = c16 & 7;
        const float* av = (c16 < 8) ? a1s : a1d;
        float acc = 0.f;
#pragma unroll 8
        for (int c = 0; c < 64; c++)
            acc = fmaf(W1[k * 512 + hd * 64 + c], av[hd * 64 + c], acc);
        unsigned short h = f2bf(acc);
        W1aThi[c16 * 128 + k] = h;
        W1aTlo[c16 * 128 + k] = f2bf(acc - bf2f(h));
    } else {
        int j = i - (128 * 512 + 512 * 16 + 128 * 16);
        if (j < N_NODES) cursor[j] = 0;
    }
}

/* ---------------- merged: edge scatter-append (blocks < SCAT) + layer-1 GEMM ---------------- */
#define SCAT 256
__global__ __launch_bounds__(256) void k_sg1(const int* __restrict__ ei,
                                             int* __restrict__ cursor,
                                             int* __restrict__ colsrc,
                                             const float* __restrict__ x,
                                             const unsigned short* __restrict__ W1hiT,
                                             const unsigned short* __restrict__ W1aThi,
                                             const unsigned short* __restrict__ W1aTlo,
                                             unsigned short* __restrict__ h1b,
                                             float* __restrict__ al1s,
                                             float* __restrict__ al1d) {
    __shared__ unsigned short xs_hi[64 * 136];
    if (blockIdx.x < SCAT) {
        int gtid = blockIdx.x * 256 + threadIdx.x;
        for (int i = gtid; i < N_TOT; i += SCAT * 256) {
            int src, dst;
            if (i < N_EDGES) { src = ei[i]; dst = ei[N_EDGES + i]; }
            else             { src = dst = i - N_EDGES; }
            int pos = atomicAdd(&cursor[dst], 1);
            if (pos < CAP) colsrc[dst * CAP + pos] = src;
        }
        return;
    }
    const int t = threadIdx.x;
    const int rb = (blockIdx.x - SCAT) * 64;

#pragma unroll
    for (int i = 0; i < 8; i++) {
        int idx = t + 256 * i;           /* 2048 float4 total */
        int r = idx >> 5;                /* 32 float4 per row */
        int k = (idx & 31) * 4;
        int gr = rb + r;
        float4 v = make_float4(0.f, 0.f, 0.f, 0.f);
        if (gr < N_NODES) v = *reinterpret_cast<const float4*>(&x[gr * 128 + k]);
        ushort4 hi;
        hi.x = f2bf(v.x); hi.y = f2bf(v.y); hi.z = f2bf(v.z); hi.w = f2bf(v.w);
        *reinterpret_cast<ushort4*>(&xs_hi[r * 136 + k]) = hi;
    }
    __syncthreads();

    const int lane = t & 63;
    const int w = t >> 6;
    const int kbase = (lane >> 4) * 8;
    const int colloc = (w << 4) + (lane & 15);

#pragma unroll
    for (int pr = 0; pr < 4; pr++) {
        bf16x8 bhi[2][4];
#pragma unroll
        for (int si = 0; si < 2; si++) {
            int col = (pr * 2 + si) * 64 + colloc;
#pragma unroll
            for (int kc = 0; kc < 4; kc++)
                bhi[si][kc] = *reinterpret_cast<const bf16x8*>(&W1hiT[col * 128 + kc * 32 + kbase]);
        }
#pragma unroll
        for (int mt = 0; mt < 4; mt++) {
            const int arow = mt * 16 + (lane & 15);
            bf16x8 ah[4];
#pragma unroll
            for (int kc = 0; kc < 4; kc++)
                ah[kc] = *reinterpret_cast<const bf16x8*>(&xs_hi[arow * 136 + kc * 32 + kbase]);
#pragma unroll
            for (int si = 0; si < 2; si++) {
                f32x4 acc = {0.f, 0.f, 0.f, 0.f};
#pragma unroll
                for (int kc = 0; kc < 4; kc++)
                    acc = __builtin_amdgcn_mfma_f32_16x16x32_bf16(ah[kc], bhi[si][kc], acc, 0, 0, 0);
                const int col = (pr * 2 + si) * 64 + colloc;
                const int r0 = rb + mt * 16 + (lane >> 4) * 4;
#pragma unroll
                for (int r = 0; r < 4; r++) {
                    int row = r0 + r;
                    if (row < N_NODES) h1b[row * 512 + col] = f2bf(acc[r]);
                }
            }
        }
    }

    /* fused attention-half tile: wave w handles m-tile w, cols 0..15 of W1a (hi+lo) */
    {
        const int c16 = lane & 15;
        bf16x8 bh[4], bl[4];
#pragma unroll
        for (int kc = 0; kc < 4; kc++) {
            bh[kc] = *reinterpret_cast<const bf16x8*>(&W1aThi[c16 * 128 + kc * 32 + kbase]);
            bl[kc] = *reinterpret_cast<const bf16x8*>(&W1aTlo[c16 * 128 + kc * 32 + kbase]);
        }
        const int arow = (w << 4) + (lane & 15);
        f32x4 acc = {0.f, 0.f, 0.f, 0.f};
#pragma unroll
        for (int kc = 0; kc < 4; kc++) {
            bf16x8 ah = *reinterpret_cast<const bf16x8*>(&xs_hi[arow * 136 + kc * 32 + kbase]);
            acc = __builtin_amdgcn_mfma_f32_16x16x32_bf16(ah, bh[kc], acc, 0, 0, 0);
            acc = __builtin_amdgcn_mfma_f32_16x16x32_bf16(ah, bl[kc], acc, 0, 0, 0);
        }
        const int r0 = rb + (w << 4) + (lane >> 4) * 4;
#pragma unroll
        for (int r = 0; r < 4; r++) {
            int row = r0 + r;
            if (row < N_NODES) {
                if (c16 < 8) al1s[row * 8 + c16] = acc[r];
                else         al1d[row * 8 + (c16 - 8)] = acc[r];
            }
        }
    }
}

/* ---------------- Layer 1 softmax+agg FUSED with layer-2 GEMM ----------------
   One wave per dst node (4/block, 256 thr) — r1 skeleton (proven 70.6 us).
   Gather rebuilt for MLP: source ids live in LDS (one int4 read replaces the
   serial 4-shuffle chain); main loop consumes 8 edges/round through NAMED
   registers e0..e7 (no arrays -> compiler cannot reuse buffers -> 8 loads
   genuinely in flight); tail is one weight-0-padded 4-group (pad reads row 0,
   L1-hot, <=3 wasted rows).
   Epilogue: r1-exact — 4 rows -> LDS, syncthreads, wave 0 MFMA 4x512@512x16. */
__global__ __launch_bounds__(256) void k_agg1(const int* __restrict__ cursor,
                                              const int* __restrict__ colsrc,
                                              const float* __restrict__ al1s,
                                              const float* __restrict__ al1d,
                                              const unsigned short* __restrict__ h1b,
                                              const float* __restrict__ b1,
                                              const unsigned short* __restrict__ W2hiT,
                                              const float* __restrict__ a2s,
                                              const float* __restrict__ a2d,
                                              unsigned short* __restrict__ h2b,
                                              float* __restrict__ al2s,
                                              float* __restrict__ al2d) {
    __shared__ float pw[4][8 * 66];                      /* per-wave edge weights, head-major */
    __shared__ int se[4][64];                            /* per-wave edge source ids */
    __shared__ __align__(16) unsigned short vs[4 * 520]; /* 4 finished h1 rows, bf16, padded  */
    const int wid  = threadIdx.x >> 6;
    const int lane = threadIdx.x & 63;
    const int n0 = blockIdx.x * 4;
    const int n  = n0 + wid;                             /* grid exact: n < N_NODES always */
    const int cnt = min(cursor[n], CAP);
    const int eb = n * CAP;
    const int h  = lane >> 3;                            /* head owned by this lane */
    const int c8 = lane << 3;                            /* first of 8 owned channels */
    float* mypw = pw[wid];
    const int* mysrc = se[wid];

    const float4 d0 = *reinterpret_cast<const float4*>(&al1d[n * 8]);
    const float4 d1 = *reinterpret_cast<const float4*>(&al1d[n * 8 + 4]);

    int s0 = 0;
    float p[8];
    if (lane < cnt) {
        s0 = colsrc[eb + lane];
        const float4 u0 = *reinterpret_cast<const float4*>(&al1s[s0 * 8]);
        const float4 u1 = *reinterpret_cast<const float4*>(&al1s[s0 * 8 + 4]);
        p[0] = __expf(fminf(lrelu(u0.x + d0.x), 60.f));
        p[1] = __expf(fminf(lrelu(u0.y + d0.y), 60.f));
        p[2] = __expf(fminf(lrelu(u0.z + d0.z), 60.f));
        p[3] = __expf(fminf(lrelu(u0.w + d0.w), 60.f));
        p[4] = __expf(fminf(lrelu(u1.x + d1.x), 60.f));
        p[5] = __expf(fminf(lrelu(u1.y + d1.y), 60.f));
        p[6] = __expf(fminf(lrelu(u1.z + d1.z), 60.f));
        p[7] = __expf(fminf(lrelu(u1.w + d1.w), 60.f));
    } else {
#pragma unroll
        for (int hh = 0; hh < 8; hh++) p[hh] = 0.f;
    }
    se[wid][lane] = s0;                                  /* pad lanes: s0=0 -> row 0, weight 0 */
#pragma unroll
    for (int hh = 0; hh < 8; hh++) mypw[hh * 66 + lane] = p[hh];

    float acc[8] = {0.f, 0.f, 0.f, 0.f, 0.f, 0.f, 0.f, 0.f};
    float sm = 0.f;
    const int pwh = h * 66;

    int j = 0;
    /* 8-edge rounds: named regs -> 8 loads in flight */
    for (; j + 7 < cnt; j += 8) {
        int4 sa = *reinterpret_cast<const int4*>(&mysrc[j]);
        int4 sb = *reinterpret_cast<const int4*>(&mysrc[j + 4]);
        u16x8 e0 = *reinterpret_cast<const u16x8*>(&h1b[sa.x * 512 + c8]);
        u16x8 e1 = *reinterpret_cast<const u16x8*>(&h1b[sa.y * 512 + c8]);
        u16x8 e2 = *reinterpret_cast<const u16x8*>(&h1b[sa.z * 512 + c8]);
        u16x8 e3 = *reinterpret_cast<const u16x8*>(&h1b[sa.w * 512 + c8]);
        u16x8 e4 = *reinterpret_cast<const u16x8*>(&h1b[sb.x * 512 + c8]);
        u16x8 e5 = *reinterpret_cast<const u16x8*>(&h1b[sb.y * 512 + c8]);
        u16x8 e6 = *reinterpret_cast<const u16x8*>(&h1b[sb.z * 512 + c8]);
        u16x8 e7 = *reinterpret_cast<const u16x8*>(&h1b[sb.w * 512 + c8]);
        float w0 = mypw[pwh + j + 0], w1 = mypw[pwh + j + 1];
        float w2 = mypw[pwh + j + 2], w3 = mypw[pwh + j + 3];
        float w4 = mypw[pwh + j + 4], w5 = mypw[pwh + j + 5];
        float w6 = mypw[pwh + j + 6], w7 = mypw[pwh + j + 7];
        sm += ((w0 + w1) + (w2 + w3)) + ((w4 + w5) + (w6 + w7));
#pragma unroll
        for (int c = 0; c < 8; c++) {
            float t = fmaf(w0, bf2f(e0[c]), acc[c]);
            t = fmaf(w1, bf2f(e1[c]), t);
            t = fmaf(w2, bf2f(e2[c]), t);
            t = fmaf(w3, bf2f(e3[c]), t);
            t = fmaf(w4, bf2f(e4[c]), t);
            t = fmaf(w5, bf2f(e5[c]), t);
            t = fmaf(w6, bf2f(e6[c]), t);
            acc[c] = fmaf(w7, bf2f(e7[c]), t);
        }
    }
    /* padded 4-edge tail rounds (entries >= cnt have weight 0, source row 0) */
    for (; j < cnt; j += 4) {
        int4 sa = *reinterpret_cast<const int4*>(&mysrc[j]);
        u16x8 e0 = *reinterpret_cast<const u16x8*>(&h1b[sa.x * 512 + c8]);
        u16x8 e1 = *reinterpret_cast<const u16x8*>(&h1b[sa.y * 512 + c8]);
        u16x8 e2 = *reinterpret_cast<const u16x8*>(&h1b[sa.z * 512 + c8]);
        u16x8 e3 = *reinterpret_cast<const u16x8*>(&h1b[sa.w * 512 + c8]);
        float w0 = mypw[pwh + j + 0], w1 = mypw[pwh + j + 1];
        float w2 = mypw[pwh + j + 2], w3 = mypw[pwh + j + 3];
        sm += (w0 + w1) + (w2 + w3);
#pragma unroll
        for (int c = 0; c < 8; c++) {
            float t = fmaf(w0, bf2f(e0[c]), acc[c]);
            t = fmaf(w1, bf2f(e1[c]), t);
            t = fmaf(w2, bf2f(e2[c]), t);
            acc[c] = fmaf(w3, bf2f(e3[c]), t);
        }
    }

    const float inv = 1.f / sm;
    const float4 ba = *reinterpret_cast<const float4*>(&b1[c8]);
    const float4 bb = *reinterpret_cast<const float4*>(&b1[c8 + 4]);
    float v[8];
    v[0] = acc[0] * inv + ba.x; v[1] = acc[1] * inv + ba.y;
    v[2] = acc[2] * inv + ba.z; v[3] = acc[3] * inv + ba.w;
    v[4] = acc[4] * inv + bb.x; v[5] = acc[5] * inv + bb.y;
    v[6] = acc[6] * inv + bb.z; v[7] = acc[7] * inv + bb.w;
#pragma unroll
    for (int k = 0; k < 8; k++)
        v[k] = v[k] > 0.f ? v[k] : __expf(v[k]) - 1.f;
    u16x8 o;
#pragma unroll
    for (int k = 0; k < 8; k++) o[k] = f2bf(v[k]);
    *reinterpret_cast<u16x8*>(&vs[wid * 520 + c8]) = o;

    __syncthreads();

    if (wid == 0) {
        /* 4x512 @ 512x16 matvec for the block's 4 nodes via MFMA.
           A rows wrapped lane&3: rows 4-15 duplicate rows 0-3; their C rows are discarded. */
        const int col   = lane & 15;
        const int kbase = (lane >> 4) << 3;
        const int rowm  = lane & 3;
        f32x4 a2 = {0.f, 0.f, 0.f, 0.f};
#pragma unroll 4
        for (int kc = 0; kc < 16; kc++) {
            bf16x8 bh = *reinterpret_cast<const bf16x8*>(&W2hiT[col * 512 + kc * 32 + kbase]);
            bf16x8 ah = *reinterpret_cast<const bf16x8*>(&vs[rowm * 520 + kc * 32 + kbase]);
            a2 = __builtin_amdgcn_mfma_f32_16x16x32_bf16(ah, bh, a2, 0, 0, 0);
        }
        /* C: row=(lane>>4)*4+r, col=lane&15 -> lanes 0-15 hold rows 0-3 (the 4 nodes) */
        if (lane < 16) {
            const float as_c = a2s[col];
            const float ad_c = a2d[col];
#pragma unroll
            for (int r = 0; r < 4; r++) {
                float ps = a2[r] * as_c;
                float pd = a2[r] * ad_c;
                ps += __shfl_xor(ps, 1, 64); pd += __shfl_xor(pd, 1, 64);
                ps += __shfl_xor(ps, 2, 64); pd += __shfl_xor(pd, 2, 64);
                ps += __shfl_xor(ps, 4, 64); pd += __shfl_xor(pd, 4, 64);
                ps += __shfl_xor(ps, 8, 64); pd += __shfl_xor(pd, 8, 64);
                h2b[(n0 + r) * 16 + col] = f2bf(a2[r]);
                if (lane == 0) { al2s[n0 + r] = ps; al2d[n0 + r] = pd; }
            }
        }
    }
}

/* ---------------- Layer 2 aggregation -> out (16-edge-parallel, 8B h2b loads) ----------------
   16 edge slots x 4 lanes/edge (ushort4 = 4 channels each). Typical cnt<=16 ->
   ONE gather latency round (old 8-slot layout needed two). */
__global__ __launch_bounds__(256) void k_agg2(const int* __restrict__ cursor,
                                              const int* __restrict__ colsrc,
                                              const float* __restrict__ al2s,
                                              const float* __restrict__ al2d,
                                              const unsigned short* __restrict__ h2b,
                                              const float* __restrict__ b2,
                                              float* __restrict__ out) {
    int wv = threadIdx.x >> 6, lane = threadIdx.x & 63;
    int n = blockIdx.x * 4 + wv;
    if (n >= N_NODES) return;
    int cnt = min(cursor[n], CAP);
    const int eb = n * CAP;
    float ald = al2d[n];
    int q = lane >> 2;            /* edge slot 0..15 */
    int c4 = (lane & 3) << 2;     /* 4-channel base */
    float a0 = 0.f, a1 = 0.f, a2 = 0.f, a3 = 0.f, smL = 0.f;
    for (int e = q; e < cnt; e += 16) {
        int s = colsrc[eb + e];
        float w = __expf(fminf(lrelu(al2s[s] + ald), 60.f));
        ushort4 v = *reinterpret_cast<const ushort4*>(&h2b[s * 16 + c4]);
        smL += w;
        a0 = fmaf(w, bf2f(v.x), a0);
        a1 = fmaf(w, bf2f(v.y), a1);
        a2 = fmaf(w, bf2f(v.z), a2);
        a3 = fmaf(w, bf2f(v.w), a3);
    }
#pragma unroll
    for (int off = 4; off < 64; off <<= 1) {
        a0 += __shfl_xor(a0, off, 64);
        a1 += __shfl_xor(a1, off, 64);
        a2 += __shfl_xor(a2, off, 64);
        a3 += __shfl_xor(a3, off, 64);
        smL += __shfl_xor(smL, off, 64);
    }
    if (q == 0) {
        float inv = 1.f / smL;
        const float4 bb = *reinterpret_cast<const float4*>(&b2[c4]);
        float4 r;
        r.x = a0 * inv + bb.x;
        r.y = a1 * inv + bb.y;
        r.z = a2 * inv + bb.z;
        r.w = a3 * inv + bb.w;
        *reinterpret_cast<float4*>(&out[n * 16 + c4]) = r;
    }
}

/* ---------------- launch ---------------- */
extern "C" void kernel_launch(void* const* d_in, const int* in_sizes, int n_in,
                              void* d_out, int out_size, void* d_ws, size_t ws_size,
                              hipStream_t stream) {
    const float* x   = (const float*)d_in[0];
    const int*   ei  = (const int*)d_in[1];
    const float* W1  = (const float*)d_in[2];
    const float* a1s = (const float*)d_in[3];
    const float* a1d = (const float*)d_in[4];
    const float* b1  = (const float*)d_in[5];
    const float* W2  = (const float*)d_in[6];
    const float* a2s = (const float*)d_in[7];
    const float* a2d = (const float*)d_in[8];
    const float* b2  = (const float*)d_in[9];
    float* out = (float*)d_out;

    char* ws = (char*)d_ws;
    unsigned short* h1b = (unsigned short*)(ws + 0);            /* N*512 bf16 = 51.2 MB */
    unsigned short* h2b = (unsigned short*)(ws + 102400000);    /* N*16 bf16 = 1.6 MB */
    float* al1s = (float*)(ws + 105600000);    /* N*8 */
    float* al1d = (float*)(ws + 107200000);    /* N*8 */
    float* al2s = (float*)(ws + 108800000);    /* N */
    float* al2d = (float*)(ws + 109000000);    /* N */
    int* cursor = (int*)(ws + 109200000);      /* N ints */
    int* colsrc = (int*)(ws + 109400000);      /* N*CAP ints = 12.8 MB */
    unsigned short* W1hiT  = (unsigned short*)(ws + 122200000); /* 512x128 bf16 */
    unsigned short* W2hiT  = (unsigned short*)(ws + 122336000); /* 16x512 bf16 */
    unsigned short* W1aThi = (unsigned short*)(ws + 122352384); /* 16x128 bf16 */
    unsigned short* W1aTlo = (unsigned short*)(ws + 122356480);

    /* init: weight prep + cursor zero (one launch) */
    k_init<<<492, 256, 0, stream>>>(W1, W1hiT, W2, W2hiT, a1s, a1d, W1aThi, W1aTlo, cursor);

    /* scatter-append + layer-1 GEMM (merged) */
    k_sg1<<<SCAT + (N_NODES + 63) / 64, 256, 0, stream>>>(ei, cursor, colsrc, x,
                                                          W1hiT, W1aThi, W1aTlo,
                                                          h1b, al1s, al1d);

    /* layer 1 aggregation fused with layer-2 GEMM (8-wide named-reg gather) */
    k_agg1<<<(N_NODES + 3) / 4, 256, 0, stream>>>(cursor, colsrc, al1s, al1d, h1b, b1,
                                                  W2hiT, a2s, a2d, h2b, al2s, al2d);

    /* layer 2 aggregation */
    k_agg2<<<(N_NODES + 3) / 4, 256, 0, stream>>>(cursor, colsrc, al2s, al2d, h2b, b2, out);
}